// Round 5
// baseline (799.000 us; speedup 1.0000x reference)
//
#include <hip/hip_runtime.h>
#include <stdint.h>

// ParentGRU fused: 12x (65536x512)@(512x512) GEMMs + gates, via bf16 MFMA.
// R5: 2-barrier-per-K-tile compiler-scheduled 256x256 GEMM (T2 swizzle +
// counted vmcnt(8) 2-tile-deep prefetch + T5 setprio). Replaces the 8-phase
// lockstep schedule whose 8 barriers + 4 lgkm full-drains per K-tile were the
// measured stall (MfmaUtil 26.5% with nothing saturated).
//
// ws layout (bytes):
//   B1  @ 0           : 1536x1536 bf16   B2 @ 4,718,592 : 512x1536 bf16
//   hr  @ 6,291,456   : 65536x512 bf16 (h*sig(r))
//   pr1 @ 73,400,320  : 65536x512 bf16 (p*sig(r1))
//   Xb  @ 140,509,184 / Hb @ 207,618,048 / Pb @ 274,726,912 : bf16 inputs
// att parked fp32 in d_out between k1 and k2.

typedef unsigned short u16;
using bf16x8 = __attribute__((ext_vector_type(8))) __bf16;
using f32x4  = __attribute__((ext_vector_type(4))) float;

__device__ __forceinline__ u16 f2bf(float f) {
    __bf16 b = (__bf16)f;
    union { __bf16 b; u16 u; } v; v.b = b;
    return v.u;
}
__device__ __forceinline__ uint32_t f2bf2(float lo, float hi) {
    return (uint32_t)f2bf(lo) | ((uint32_t)f2bf(hi) << 16);
}
__device__ __forceinline__ float bf2f(u16 s) {
    union { uint32_t u; float f; } v; v.u = ((uint32_t)s) << 16;
    return v.f;
}
__device__ __forceinline__ void load_lds16(const void* g, void* l) {
    __builtin_amdgcn_global_load_lds(
        (const __attribute__((address_space(1))) uint32_t*)g,
        (__attribute__((address_space(3))) uint32_t*)l, 16, 0, 0);
}
__device__ __forceinline__ void fence_bar() {
    asm volatile("" ::: "memory");
    __builtin_amdgcn_s_barrier();
    asm volatile("" ::: "memory");
}

// ---------------- weight packing ----------------
__global__ void prep_weights(
    const float* __restrict__ wa, const float* __restrict__ ua, const float* __restrict__ pa,
    const float* __restrict__ wrg, const float* __restrict__ ur, const float* __restrict__ pr,
    const float* __restrict__ wr1, const float* __restrict__ ur1, const float* __restrict__ pr1,
    const float* __restrict__ wcc, const float* __restrict__ uc, const float* __restrict__ pc,
    u16* __restrict__ B1, u16* __restrict__ B2)
{
    int idx = blockIdx.x * 256 + threadIdx.x;
    const int T1 = 1536 * 1536;
    if (idx < T1) {
        int n = idx / 1536, k = idx - n * 1536;
        int g = n >> 9, nn = n & 511;
        int o = k >> 9, kk = k & 511;
        const float* s;
        if (g == 0)      s = (o == 0) ? wa  : (o == 1) ? ua  : pa;
        else if (g == 1) s = (o == 0) ? wrg : (o == 1) ? ur  : pr;
        else             s = (o == 0) ? wr1 : (o == 1) ? ur1 : pr1;
        B1[idx] = f2bf(s[nn * 512 + kk]);
    } else {
        int j = idx - T1;
        if (j < 512 * 1536) {
            int n = j / 1536, k = j - n * 1536;
            int o = k >> 9, kk = k & 511;
            const float* s = (o == 0) ? wcc : (o == 1) ? uc : pc;
            B2[j] = f2bf(s[n * 512 + kk]);
        }
    }
}

// ---------------- input cast: X,H,P fp32 -> bf16 ----------------
__global__ void cast_inputs(const float* __restrict__ X, const float* __restrict__ H,
                            const float* __restrict__ P,
                            u16* __restrict__ Xb, u16* __restrict__ Hb, u16* __restrict__ Pb)
{
    const long long MAT8 = (65536LL * 512) / 8;
    for (long long t = (long long)blockIdx.x * 256 + threadIdx.x;
         t < 3 * MAT8; t += (long long)gridDim.x * 256) {
        int m = (int)(t >> 22);
        long long e = (t & (MAT8 - 1)) * 8;
        const float* s = (m == 0) ? X : (m == 1) ? H : P;
        u16* d = (m == 0) ? Xb : (m == 1) ? Hb : Pb;
        f32x4 a = *(const f32x4*)(s + e);
        f32x4 b = *(const f32x4*)(s + e + 4);
        uint4 q;
        q.x = f2bf2(a.x, a.y); q.y = f2bf2(a.z, a.w);
        q.z = f2bf2(b.x, b.y); q.w = f2bf2(b.z, b.w);
        *(uint4*)(d + e) = q;
    }
}

// =============== 2-barrier 256x256 GEMM (big path) ===============
// MODE 1: C = A@B1^T, A=[Xb|Hb|Pb] (K=1536), N=1536; sigmoid epilogue.
// MODE 2: A=[Xb|hr|pr1], B=B2, N=512; tanh + final combine epilogue.
template<int MODE>
__global__ __launch_bounds__(512, 2)
void gemm256(const u16* __restrict__ A0, const u16* __restrict__ A1s, const u16* __restrict__ A2s,
             const u16* __restrict__ Bw,
             const float* __restrict__ bias0, const float* __restrict__ bias1,
             const float* __restrict__ bias2,
             const u16* __restrict__ HbP, const u16* __restrict__ PbP,
             const float* __restrict__ Hf,
             float* __restrict__ outp, u16* __restrict__ hrw, u16* __restrict__ pr1w)
{
    __shared__ u16 lds[65536];     // [buf2][A 256x64 | B 256x64], 128 KiB
    constexpr int NT = 24;

    const int tid  = threadIdx.x;
    const int lane = tid & 63;
    const int wv   = tid >> 6;
    const int wr   = wv >> 2;      // 0..1  (M 128-half)
    const int wc   = wv & 3;       // 0..3  (N 64-slice)

    int panel, ntl;
    const int xcd = blockIdx.x & 7;
    const int idx = blockIdx.x >> 3;
    if (MODE == 1) { panel = xcd * 32 + idx / 6;    ntl = idx % 6; }
    else           { panel = xcd * 32 + (idx >> 1); ntl = idx & 1; }
    const int m0 = panel * 256;
    const int n0 = ntl * 256;

    // ---- staging geometry (T2: LDS linear, global col pre-swizzled) ----
    const int srow = tid >> 3;                    // 0..63
    const int scg  = ((tid & 7) ^ (srow & 7)) * 8;
    const int ldst = srow * 64 + (tid & 7) * 8;   // u16 units

    const int ofsA = srow * 512 + scg;
    const int ofsB = srow * 1536 + scg;
    const u16* const bA0 = A0  + (size_t)m0 * 512;
    const u16* const bA1 = A1s + (size_t)m0 * 512;
    const u16* const bA2 = A2s + (size_t)m0 * 512;
    const u16* const bB  = Bw  + (size_t)n0 * 1536;
    u16* const ldA = lds + ldst;
    u16* const ldB = lds + 16384 + ldst;

    // ---- fragment geometry (mfma 16x16x32) ----
    const int fr = lane & 15;
    const int fk = (lane >> 4) * 8;
    const int sw = (lane & 7) * 8;          // read-side XOR (row&7 == lane&7)
    const int c0 = fk ^ sw;
    const int c1 = (32 + fk) ^ sw;
    const int aOff = (wr * 128 + fr) * 64;          // + m*1024
    const int bOff = 16384 + (wc * 64 + fr) * 64;   // + j*1024

    f32x4 acc[8][4];
    const f32x4 vzero = {0.0f, 0.0f, 0.0f, 0.0f};
#pragma unroll
    for (int i = 0; i < 8; ++i)
#pragma unroll
        for (int j = 0; j < 4; ++j) acc[i][j] = vzero;

    // full-tile staging: 4 loads A + 4 loads B per thread-call (256 rows x 64 k)
    auto stA = [&](int T) {
        const u16* src = (T < 8) ? bA0 : (T < 16) ? bA1 : bA2;
        const u16* g = src + (T & 7) * 64 + ofsA;
        u16* l = ldA + (T & 1) * 32768;
        load_lds16(g,             l);
        load_lds16(g +  64 * 512, l + 4096);
        load_lds16(g + 128 * 512, l + 8192);
        load_lds16(g + 192 * 512, l + 12288);
    };
    auto stB = [&](int T) {
        const u16* g = bB + T * 64 + ofsB;
        u16* l = ldB + (T & 1) * 32768;
        load_lds16(g,              l);
        load_lds16(g +  64 * 1536, l + 4096);
        load_lds16(g + 128 * 1536, l + 8192);
        load_lds16(g + 192 * 1536, l + 12288);
    };

    // prologue: stage tiles 0 and 1 (8 loads each)
    stA(0); stB(0);
    stA(1); stB(1);
    asm volatile("s_waitcnt vmcnt(8)" ::: "memory");   // tile0 landed
    fence_bar();

    for (int T = 0; T < NT; ++T) {
        const int cb = (T & 1) * 32768;
        const u16* const pa0 = lds + (cb + aOff + c0);
        const u16* const pa1 = lds + (cb + aOff + c1);
        const u16* const pb0 = lds + (cb + bOff + c0);
        const u16* const pb1 = lds + (cb + bOff + c1);

        // ---- read all fragments + MFMA, compiler-scheduled (no inner barriers,
        //      no full lgkm drains; compiler emits fine-grained lgkmcnt(N)) ----
        bf16x8 bF[4][2];
#pragma unroll
        for (int j = 0; j < 4; ++j) {
            bF[j][0] = *(const bf16x8*)(pb0 + j * 1024);
            bF[j][1] = *(const bf16x8*)(pb1 + j * 1024);
        }
        bf16x8 aF0[4][2];
#pragma unroll
        for (int m = 0; m < 4; ++m) {
            aF0[m][0] = *(const bf16x8*)(pa0 + m * 1024);
            aF0[m][1] = *(const bf16x8*)(pa1 + m * 1024);
        }
        __builtin_amdgcn_s_setprio(1);
#pragma unroll
        for (int m = 0; m < 4; ++m)
#pragma unroll
            for (int j = 0; j < 4; ++j)
#pragma unroll
                for (int ks = 0; ks < 2; ++ks)
                    acc[m][j] = __builtin_amdgcn_mfma_f32_16x16x32_bf16(
                        aF0[m][ks], bF[j][ks], acc[m][j], 0, 0, 0);
        __builtin_amdgcn_s_setprio(0);
        bf16x8 aF1[4][2];
#pragma unroll
        for (int m = 0; m < 4; ++m) {
            aF1[m][0] = *(const bf16x8*)(pa0 + (4 + m) * 1024);
            aF1[m][1] = *(const bf16x8*)(pa1 + (4 + m) * 1024);
        }
        __builtin_amdgcn_s_setprio(1);
#pragma unroll
        for (int m = 0; m < 4; ++m)
#pragma unroll
            for (int j = 0; j < 4; ++j)
#pragma unroll
                for (int ks = 0; ks < 2; ++ks)
                    acc[4 + m][j] = __builtin_amdgcn_mfma_f32_16x16x32_bf16(
                        aF1[m][ks], bF[j][ks], acc[4 + m][j], 0, 0, 0);
        __builtin_amdgcn_s_setprio(0);

        // ---- tile boundary: free buf cb, stage T+2 into it, drain T+1 ----
        fence_bar();                              // all waves done reading buf cb
        if (T < NT - 2) {
            stA(T + 2); stB(T + 2);               // into buf cb (now free)
            asm volatile("s_waitcnt vmcnt(8)" ::: "memory");   // T+1 landed, T+2 in flight
        } else if (T == NT - 2) {
            asm volatile("s_waitcnt vmcnt(0)" ::: "memory");   // last tile landed
        }
        fence_bar();
    }

    // ---- epilogue (32-bit offsets) ----
    const int rbase = m0 + wr * 128 + (lane >> 4) * 4;
    if (MODE == 1) {
        const int g = ntl >> 1;   // 0:att 1:r 2:r1
        const float* bias = (g == 0) ? bias0 : (g == 1) ? bias1 : bias2;
        const int ncb = (ntl & 1) * 256 + wc * 64;
#pragma unroll
        for (int i = 0; i < 8; ++i)
#pragma unroll
            for (int j = 0; j < 4; ++j) {
                const int nn = ncb + j * 16 + fr;
                const float b = bias[nn];
                int off = (rbase + i * 16) * 512 + nn;
#pragma unroll
                for (int jj = 0; jj < 4; ++jj, off += 512) {
                    float v = acc[i][j][jj] + b;
                    float s = 1.0f / (1.0f + __expf(-v));
                    if (g == 0)      outp[off] = s;
                    else if (g == 1) hrw[off]  = f2bf(s * bf2f(HbP[off]));
                    else             pr1w[off] = f2bf(s * bf2f(PbP[off]));
                }
            }
    } else {
        const int ncb = n0 + wc * 64;
#pragma unroll
        for (int i = 0; i < 8; ++i)
#pragma unroll
            for (int j = 0; j < 4; ++j) {
                const int nn = ncb + j * 16 + fr;
                const float b = bias0[nn];
                int off = (rbase + i * 16) * 512 + nn;
#pragma unroll
                for (int jj = 0; jj < 4; ++jj, off += 512) {
                    float v = acc[i][j][jj] + b;
                    float e = __expf(2.0f * v);
                    float ct = 1.0f - 2.0f / (e + 1.0f);   // tanh, inf-safe
                    float a = outp[off];                     // att parked by k1
                    outp[off] = a * ct + (1.0f - a) * Hf[off];
                }
            }
    }
}

// =============== small-ws fallback: proven R2 128x128 kernels ===============
__global__ __launch_bounds__(256, 2)
void k1_small(const float* __restrict__ X, const float* __restrict__ H,
              const float* __restrict__ P, const u16* __restrict__ B1,
              const float* __restrict__ ba, const float* __restrict__ br,
              const float* __restrict__ br1,
              float* __restrict__ attf, u16* __restrict__ hrw, u16* __restrict__ pr1w)
{
    __shared__ u16 Ab[2][128 * 64];
    __shared__ u16 Bb[2][128 * 64];
    const int tid = threadIdx.x, lane = tid & 63, w = tid >> 6;
    const int wr = w >> 1, wc = w & 1;
    const int bid = blockIdx.x, xcd = bid & 7, idx = bid >> 3;
    const int panel = idx / 12, ntl = idx - panel * 12;
    const int m0 = (xcd * 64 + panel) * 128, n0 = ntl * 128;
    const int srow = w * 32 + (lane >> 3);
    const int scol = ((lane & 7) ^ (lane >> 3)) * 8;
    const int arow = tid >> 4, acol = (tid & 15) * 4;
    const int aswz = acol ^ ((arow & 7) << 3);
    f32x4 acc[4][4];
    const f32x4 vz = {0, 0, 0, 0};
#pragma unroll
    for (int i = 0; i < 4; ++i)
#pragma unroll
        for (int j = 0; j < 4; ++j) acc[i][j] = vz;
    f32x4 areg[8];
    auto issueA = [&](int kt) {
        const float* src = (kt < 8) ? X : (kt < 16) ? H : P;
        const float* base = src + (size_t)(m0 + arow) * 512 + (kt & 7) * 64 + acol;
#pragma unroll
        for (int rr = 0; rr < 8; ++rr)
            areg[rr] = *(const f32x4*)(base + (size_t)(rr * 16) * 512);
    };
    auto writeA = [&](int nb) {
#pragma unroll
        for (int rr = 0; rr < 8; ++rr) {
            uint2 q; q.x = f2bf2(areg[rr].x, areg[rr].y);
            q.y = f2bf2(areg[rr].z, areg[rr].w);
            *(uint2*)&Ab[nb][(arow + rr * 16) * 64 + aswz] = q;
        }
    };
    auto issueB = [&](int kt, int nb) {
        const u16* gb = B1 + (size_t)(n0 + srow) * 1536 + kt * 64 + scol;
        u16* lb = &Bb[nb][(w * 32) * 64];
#pragma unroll
        for (int c = 0; c < 4; ++c)
            load_lds16(gb + (size_t)c * 8 * 1536, lb + c * 8 * 64);
    };
    auto compute = [&](int cb) {
        const int rsw = (lane & 7) << 3, rb = lane & 15, hi8 = (lane >> 4) * 8;
#pragma unroll
        for (int ks = 0; ks < 2; ++ks) {
            bf16x8 af[4], bfr[4];
            const int col = (ks * 32 + hi8) ^ rsw;
#pragma unroll
            for (int fm = 0; fm < 4; ++fm)
                af[fm] = *(const bf16x8*)&Ab[cb][(wr * 64 + fm * 16 + rb) * 64 + col];
#pragma unroll
            for (int fn = 0; fn < 4; ++fn)
                bfr[fn] = *(const bf16x8*)&Bb[cb][(wc * 64 + fn * 16 + rb) * 64 + col];
#pragma unroll
            for (int fm = 0; fm < 4; ++fm)
#pragma unroll
                for (int fn = 0; fn < 4; ++fn)
                    acc[fm][fn] = __builtin_amdgcn_mfma_f32_16x16x32_bf16(
                        af[fm], bfr[fn], acc[fm][fn], 0, 0, 0);
        }
    };
    issueA(0); issueB(0, 0); writeA(0);
    __syncthreads();
    int cb = 0;
#pragma unroll 2
    for (int kt = 0; kt < 24; ++kt) {
        if (kt < 23) { issueA(kt + 1); issueB(kt + 1, cb ^ 1); }
        compute(cb);
        if (kt < 23) writeA(cb ^ 1);
        __syncthreads();
        cb ^= 1;
    }
    const int gate = ntl >> 2;
    const float* bias = (gate == 0) ? ba : (gate == 1) ? br : br1;
    const int nnb = (ntl & 3) * 128 + wc * 64;
    const int rl = (lane >> 4) * 4, cl = lane & 15;
#pragma unroll
    for (int fm = 0; fm < 4; ++fm)
#pragma unroll
        for (int fn = 0; fn < 4; ++fn) {
            const int nn = nnb + fn * 16 + cl;
            const float b = bias[nn];
#pragma unroll
            for (int j = 0; j < 4; ++j) {
                const int row = m0 + wr * 64 + fm * 16 + rl + j;
                const size_t off = (size_t)row * 512 + nn;
                float v = acc[fm][fn][j] + b;
                float s = 1.0f / (1.0f + __expf(-v));
                if (gate == 0)      attf[off] = s;
                else if (gate == 1) hrw[off]  = f2bf(s * H[off]);
                else                pr1w[off] = f2bf(s * P[off]);
            }
        }
}

__global__ __launch_bounds__(256, 2)
void k2_small(const float* __restrict__ X, const float* __restrict__ H,
              const u16* __restrict__ B2, const float* __restrict__ bc,
              const u16* __restrict__ hrw, const u16* __restrict__ pr1w,
              float* outp)
{
    __shared__ u16 Ab[2][128 * 64];
    __shared__ u16 Bb[2][128 * 64];
    const int tid = threadIdx.x, lane = tid & 63, w = tid >> 6;
    const int wr = w >> 1, wc = w & 1;
    const int bid = blockIdx.x, xcd = bid & 7, idx = bid >> 3;
    const int panel = idx >> 2, ntl = idx & 3;
    const int m0 = (xcd * 64 + panel) * 128, n0 = ntl * 128;
    const int srow = w * 32 + (lane >> 3);
    const int scol = ((lane & 7) ^ (lane >> 3)) * 8;
    const int arow = tid >> 4, acol = (tid & 15) * 4;
    const int aswz = acol ^ ((arow & 7) << 3);
    f32x4 acc[4][4];
    const f32x4 vz = {0, 0, 0, 0};
#pragma unroll
    for (int i = 0; i < 4; ++i)
#pragma unroll
        for (int j = 0; j < 4; ++j) acc[i][j] = vz;
    f32x4 areg[8];
    auto issueA = [&](int kt, int nb) {
        if (kt >= 8) {
            const u16* src = (kt < 16) ? hrw : pr1w;
            const u16* gb = src + (size_t)(m0 + srow) * 512 + (kt & 7) * 64 + scol;
            u16* lb = &Ab[nb][(w * 32) * 64];
#pragma unroll
            for (int c = 0; c < 4; ++c)
                load_lds16(gb + (size_t)c * 8 * 512, lb + c * 8 * 64);
        } else {
            const float* base = X + (size_t)(m0 + arow) * 512 + (kt & 7) * 64 + acol;
#pragma unroll
            for (int rr = 0; rr < 8; ++rr)
                areg[rr] = *(const f32x4*)(base + (size_t)(rr * 16) * 512);
        }
    };
    auto writeA = [&](int kt, int nb) {
        if (kt < 8) {
#pragma unroll
            for (int rr = 0; rr < 8; ++rr) {
                uint2 q; q.x = f2bf2(areg[rr].x, areg[rr].y);
                q.y = f2bf2(areg[rr].z, areg[rr].w);
                *(uint2*)&Ab[nb][(arow + rr * 16) * 64 + aswz] = q;
            }
        }
    };
    auto issueB = [&](int kt, int nb) {
        const u16* gb = B2 + (size_t)(n0 + srow) * 1536 + kt * 64 + scol;
        u16* lb = &Bb[nb][(w * 32) * 64];
#pragma unroll
        for (int c = 0; c < 4; ++c)
            load_lds16(gb + (size_t)c * 8 * 1536, lb + c * 8 * 64);
    };
    auto compute = [&](int cb) {
        const int rsw = (lane & 7) << 3, rb = lane & 15, hi8 = (lane >> 4) * 8;
#pragma unroll
        for (int ks = 0; ks < 2; ++ks) {
            bf16x8 af[4], bfr[4];
            const int col = (ks * 32 + hi8) ^ rsw;
#pragma unroll
            for (int fm = 0; fm < 4; ++fm)
                af[fm] = *(const bf16x8*)&Ab[cb][(wr * 64 + fm * 16 + rb) * 64 + col];
#pragma unroll
            for (int fn = 0; fn < 4; ++fn)
                bfr[fn] = *(const bf16x8*)&Bb[cb][(wc * 64 + fn * 16 + rb) * 64 + col];
#pragma unroll
            for (int fm = 0; fm < 4; ++fm)
#pragma unroll
                for (int fn = 0; fn < 4; ++fn)
                    acc[fm][fn] = __builtin_amdgcn_mfma_f32_16x16x32_bf16(
                        af[fm], bfr[fn], acc[fm][fn], 0, 0, 0);
        }
    };
    issueA(0, 0); issueB(0, 0); writeA(0, 0);
    __syncthreads();
    int cb = 0;
#pragma unroll 2
    for (int kt = 0; kt < 24; ++kt) {
        if (kt < 23) { issueA(kt + 1, cb ^ 1); issueB(kt + 1, cb ^ 1); }
        compute(cb);
        if (kt < 23) writeA(kt + 1, cb ^ 1);
        __syncthreads();
        cb ^= 1;
    }
    const int nnb = n0 + wc * 64;
    const int rl = (lane >> 4) * 4, cl = lane & 15;
#pragma unroll
    for (int fm = 0; fm < 4; ++fm)
#pragma unroll
        for (int fn = 0; fn < 4; ++fn) {
            const int nn = nnb + fn * 16 + cl;
            const float b = bc[nn];
#pragma unroll
            for (int j = 0; j < 4; ++j) {
                const int row = m0 + wr * 64 + fm * 16 + rl + j;
                const size_t off = (size_t)row * 512 + nn;
                float v = acc[fm][fn][j] + b;
                float e = __expf(2.0f * v);
                float ct = 1.0f - 2.0f / (e + 1.0f);
                float a = outp[off];
                outp[off] = a * ct + (1.0f - a) * H[off];
            }
        }
}

extern "C" void kernel_launch(void* const* d_in, const int* in_sizes, int n_in,
                              void* d_out, int out_size, void* d_ws, size_t ws_size,
                              hipStream_t stream)
{
    const float* X   = (const float*)d_in[0];
    const float* H   = (const float*)d_in[1];
    const float* P   = (const float*)d_in[2];
    const float* wa  = (const float*)d_in[3];
    const float* ba  = (const float*)d_in[4];
    const float* wrg = (const float*)d_in[5];
    const float* br  = (const float*)d_in[6];
    const float* wr1 = (const float*)d_in[7];
    const float* br1 = (const float*)d_in[8];
    const float* wcc = (const float*)d_in[9];
    const float* bc  = (const float*)d_in[10];
    const float* ua  = (const float*)d_in[11];
    const float* ur  = (const float*)d_in[12];
    const float* ur1 = (const float*)d_in[13];
    const float* uc  = (const float*)d_in[14];
    const float* pa  = (const float*)d_in[15];
    const float* pr  = (const float*)d_in[16];
    const float* pr1 = (const float*)d_in[17];
    const float* pc  = (const float*)d_in[18];

    char* ws = (char*)d_ws;
    u16* B1   = (u16*)(ws);
    u16* B2   = (u16*)(ws + (size_t)4718592);
    u16* hrp  = (u16*)(ws + (size_t)6291456);
    u16* pr1p = (u16*)(ws + (size_t)73400320);
    u16* Xb   = (u16*)(ws + (size_t)140509184);
    u16* Hb   = (u16*)(ws + (size_t)207618048);
    u16* Pb   = (u16*)(ws + (size_t)274726912);
    float* out = (float*)d_out;

    const bool big = ws_size >= (size_t)341835776ULL;

    prep_weights<<<12288, 256, 0, stream>>>(wa, ua, pa, wrg, ur, pr, wr1, ur1, pr1,
                                            wcc, uc, pc, B1, B2);
    if (big) {
        cast_inputs<<<3072, 256, 0, stream>>>(X, H, P, Xb, Hb, Pb);
        gemm256<1><<<1536, 512, 0, stream>>>(Xb, Hb, Pb, B1, ba, br, br1,
                                             Hb, Pb, nullptr, out, hrp, pr1p);
        gemm256<2><<<512, 512, 0, stream>>>(Xb, hrp, pr1p, B2, bc, nullptr, nullptr,
                                            nullptr, nullptr, H, out, nullptr, nullptr);
    } else {
        k1_small<<<6144, 256, 0, stream>>>(X, H, P, B1, ba, br, br1, out, hrp, pr1p);
        k2_small<<<2048, 256, 0, stream>>>(X, H, B2, bc, hrp, pr1p, out);
    }
}

// Round 6
// 738.561 us; speedup vs baseline: 1.0818x; 1.0818x over previous
//
#include <hip/hip_runtime.h>
#include <stdint.h>

// ParentGRU fused: 12x (65536x512)@(512x512) GEMMs + gates, via bf16 MFMA.
// R6: 2-phase-per-K-tile 256x256 GEMM, #pragma unroll 1 K-loop (I$-friendly),
// full-tile stage calls with vmcnt(4) cadence, T2 swizzle, T5 setprio.
//
// ws layout (bytes):
//   B1  @ 0           : 1536x1536 bf16   B2 @ 4,718,592 : 512x1536 bf16
//   hr  @ 6,291,456   : 65536x512 bf16 (h*sig(r))
//   pr1 @ 73,400,320  : 65536x512 bf16 (p*sig(r1))
//   Xb  @ 140,509,184 / Hb @ 207,618,048 / Pb @ 274,726,912 : bf16 inputs
// att parked fp32 in d_out between k1 and k2; k2 reads h from Hb (bf16).

typedef unsigned short u16;
using bf16x8 = __attribute__((ext_vector_type(8))) __bf16;
using f32x4  = __attribute__((ext_vector_type(4))) float;

__device__ __forceinline__ u16 f2bf(float f) {
    __bf16 b = (__bf16)f;
    union { __bf16 b; u16 u; } v; v.b = b;
    return v.u;
}
__device__ __forceinline__ uint32_t f2bf2(float lo, float hi) {
    return (uint32_t)f2bf(lo) | ((uint32_t)f2bf(hi) << 16);
}
__device__ __forceinline__ float bf2f(u16 s) {
    union { uint32_t u; float f; } v; v.u = ((uint32_t)s) << 16;
    return v.f;
}
__device__ __forceinline__ void load_lds16(const void* g, void* l) {
    __builtin_amdgcn_global_load_lds(
        (const __attribute__((address_space(1))) uint32_t*)g,
        (__attribute__((address_space(3))) uint32_t*)l, 16, 0, 0);
}
__device__ __forceinline__ void fence_bar() {
    asm volatile("" ::: "memory");
    __builtin_amdgcn_s_barrier();
    asm volatile("" ::: "memory");
}

// ---------------- weight packing ----------------
__global__ void prep_weights(
    const float* __restrict__ wa, const float* __restrict__ ua, const float* __restrict__ pa,
    const float* __restrict__ wrg, const float* __restrict__ ur, const float* __restrict__ pr,
    const float* __restrict__ wr1, const float* __restrict__ ur1, const float* __restrict__ pr1,
    const float* __restrict__ wcc, const float* __restrict__ uc, const float* __restrict__ pc,
    u16* __restrict__ B1, u16* __restrict__ B2)
{
    int idx = blockIdx.x * 256 + threadIdx.x;
    const int T1 = 1536 * 1536;
    if (idx < T1) {
        int n = idx / 1536, k = idx - n * 1536;
        int g = n >> 9, nn = n & 511;
        int o = k >> 9, kk = k & 511;
        const float* s;
        if (g == 0)      s = (o == 0) ? wa  : (o == 1) ? ua  : pa;
        else if (g == 1) s = (o == 0) ? wrg : (o == 1) ? ur  : pr;
        else             s = (o == 0) ? wr1 : (o == 1) ? ur1 : pr1;
        B1[idx] = f2bf(s[nn * 512 + kk]);
    } else {
        int j = idx - T1;
        if (j < 512 * 1536) {
            int n = j / 1536, k = j - n * 1536;
            int o = k >> 9, kk = k & 511;
            const float* s = (o == 0) ? wcc : (o == 1) ? uc : pc;
            B2[j] = f2bf(s[n * 512 + kk]);
        }
    }
}

// ---------------- input cast: X,H,P fp32 -> bf16 ----------------
__global__ void cast_inputs(const float* __restrict__ X, const float* __restrict__ H,
                            const float* __restrict__ P,
                            u16* __restrict__ Xb, u16* __restrict__ Hb, u16* __restrict__ Pb)
{
    const long long MAT8 = (65536LL * 512) / 8;
    for (long long t = (long long)blockIdx.x * 256 + threadIdx.x;
         t < 3 * MAT8; t += (long long)gridDim.x * 256) {
        int m = (int)(t >> 22);
        long long e = (t & (MAT8 - 1)) * 8;
        const float* s = (m == 0) ? X : (m == 1) ? H : P;
        u16* d = (m == 0) ? Xb : (m == 1) ? Hb : Pb;
        f32x4 a = *(const f32x4*)(s + e);
        f32x4 b = *(const f32x4*)(s + e + 4);
        uint4 q;
        q.x = f2bf2(a.x, a.y); q.y = f2bf2(a.z, a.w);
        q.z = f2bf2(b.x, b.y); q.w = f2bf2(b.z, b.w);
        *(uint4*)(d + e) = q;
    }
}

// =============== 2-phase 256x256 GEMM (big path) ===============
// MODE 1: C = A@B1^T, A=[Xb|Hb|Pb] (K=1536), N=1536; sigmoid epilogue.
// MODE 2: A=[Xb|hr|pr1], B=B2, N=512; tanh + final combine (h from Hb bf16).
template<int MODE>
__global__ __launch_bounds__(512, 2)
void gemm256(const u16* __restrict__ A0, const u16* __restrict__ A1s, const u16* __restrict__ A2s,
             const u16* __restrict__ Bw,
             const float* __restrict__ bias0, const float* __restrict__ bias1,
             const float* __restrict__ bias2,
             const u16* __restrict__ HbP, const u16* __restrict__ PbP,
             float* __restrict__ outp, u16* __restrict__ hrw, u16* __restrict__ pr1w)
{
    __shared__ u16 lds[65536];     // [buf2][A 256x64 | B 256x64], 128 KiB
    constexpr int NT = 24;

    const int tid  = threadIdx.x;
    const int lane = tid & 63;
    const int wv   = tid >> 6;
    const int wr   = wv >> 2;      // 0..1  (M 128-half)
    const int wc   = wv & 3;       // 0..3  (N 64-slice)

    int panel, ntl;
    const int xcd = blockIdx.x & 7;
    const int idx = blockIdx.x >> 3;
    if (MODE == 1) { panel = xcd * 32 + idx / 6;    ntl = idx % 6; }
    else           { panel = xcd * 32 + (idx >> 1); ntl = idx & 1; }
    const int m0 = panel * 256;
    const int n0 = ntl * 256;

    // ---- staging geometry (T2: LDS linear, global col pre-swizzled) ----
    const int srow = tid >> 3;                    // 0..63
    const int scg  = ((tid & 7) ^ (srow & 7)) * 8;
    const int ldst = srow * 64 + (tid & 7) * 8;   // u16 units

    const int ofsA = srow * 512 + scg;
    const int ofsB = srow * 1536 + scg;
    const u16* const bA0 = A0  + (size_t)m0 * 512;
    const u16* const bA1 = A1s + (size_t)m0 * 512;
    const u16* const bA2 = A2s + (size_t)m0 * 512;
    const u16* const bB  = Bw  + (size_t)n0 * 1536;
    u16* const ldA = lds + ldst;
    u16* const ldB = lds + 16384 + ldst;

    // ---- fragment geometry (mfma 16x16x32) ----
    const int fr = lane & 15;
    const int fk = (lane >> 4) * 8;
    const int sw = (lane & 7) * 8;          // read-side XOR (row&7 == lane&7)
    const int c0 = fk ^ sw;
    const int c1 = (32 + fk) ^ sw;
    const int aOff = (wr * 128 + fr) * 64;          // + m*1024
    const int bOff = 16384 + (wc * 64 + fr) * 64;   // + j*1024

    f32x4 acc[8][4];
    const f32x4 vzero = {0.0f, 0.0f, 0.0f, 0.0f};
#pragma unroll
    for (int i = 0; i < 8; ++i)
#pragma unroll
        for (int j = 0; j < 4; ++j) acc[i][j] = vzero;

    // full-tile staging: 4 x global_load_lds (16B) per call
    auto stA = [&](int T) {
        const u16* src = (T < 8) ? bA0 : (T < 16) ? bA1 : bA2;
        const u16* g = src + (T & 7) * 64 + ofsA;
        u16* l = ldA + (T & 1) * 32768;
        load_lds16(g,             l);
        load_lds16(g +  64 * 512, l + 4096);
        load_lds16(g + 128 * 512, l + 8192);
        load_lds16(g + 192 * 512, l + 12288);
    };
    auto stB = [&](int T) {
        const u16* g = bB + T * 64 + ofsB;
        u16* l = ldB + (T & 1) * 32768;
        load_lds16(g,              l);
        load_lds16(g +  64 * 1536, l + 4096);
        load_lds16(g + 128 * 1536, l + 8192);
        load_lds16(g + 192 * 1536, l + 12288);
    };

    // prologue: tile0 A+B, tile1 B (tile1 A staged during T=0 phaseA)
    stA(0); stB(0);
    stB(1);
    asm volatile("s_waitcnt vmcnt(4)" ::: "memory");   // tile0 landed, B(1) in flight
    fence_bar();

#pragma unroll 1
    for (int T = 0; T < NT; ++T) {
        const int cb = (T & 1) * 32768;
        const u16* const pa0 = lds + (cb + aOff + c0);
        const u16* const pa1 = lds + (cb + aOff + c1);
        const u16* const pb0 = lds + (cb + bOff + c0);
        const u16* const pb1 = lds + (cb + bOff + c1);

        // ===== phase A: B frags + A frags 0..3, stage A(T+1), 32 MFMA =====
        bf16x8 bF[4][2];
#pragma unroll
        for (int j = 0; j < 4; ++j) {
            bF[j][0] = *(const bf16x8*)(pb0 + j * 1024);
            bF[j][1] = *(const bf16x8*)(pb1 + j * 1024);
        }
        {
            bf16x8 aF[4][2];
#pragma unroll
            for (int m = 0; m < 4; ++m) {
                aF[m][0] = *(const bf16x8*)(pa0 + m * 1024);
                aF[m][1] = *(const bf16x8*)(pa1 + m * 1024);
            }
            if (T < NT - 1) stA(T + 1);            // into buf^1 (freed at boundary)
            fence_bar();
            asm volatile("s_waitcnt lgkmcnt(0)" ::: "memory");
            __builtin_amdgcn_sched_barrier(0);
            __builtin_amdgcn_s_setprio(1);
#pragma unroll
            for (int m = 0; m < 4; ++m)
#pragma unroll
                for (int j = 0; j < 4; ++j)
#pragma unroll
                    for (int ks = 0; ks < 2; ++ks)
                        acc[m][j] = __builtin_amdgcn_mfma_f32_16x16x32_bf16(
                            aF[m][ks], bF[j][ks], acc[m][j], 0, 0, 0);
            __builtin_amdgcn_s_setprio(0);
            fence_bar();                            // fences stB below vs bF reads
        }

        // ===== phase B: A frags 4..7, stage B(T+2), 32 MFMA, vmcnt gate =====
        {
            bf16x8 aG[4][2];
#pragma unroll
            for (int m = 0; m < 4; ++m) {
                aG[m][0] = *(const bf16x8*)(pa0 + (4 + m) * 1024);
                aG[m][1] = *(const bf16x8*)(pa1 + (4 + m) * 1024);
            }
            if (T < NT - 2) stB(T + 2);            // into CURRENT buf B-region (safe: post-phaseA barrier)
            fence_bar();
            asm volatile("s_waitcnt lgkmcnt(0)" ::: "memory");
            __builtin_amdgcn_sched_barrier(0);
            __builtin_amdgcn_s_setprio(1);
#pragma unroll
            for (int m = 0; m < 4; ++m)
#pragma unroll
                for (int j = 0; j < 4; ++j)
#pragma unroll
                    for (int ks = 0; ks < 2; ++ks)
                        acc[4 + m][j] = __builtin_amdgcn_mfma_f32_16x16x32_bf16(
                            aG[m][ks], bF[j][ks], acc[4 + m][j], 0, 0, 0);
            __builtin_amdgcn_s_setprio(0);
            // gate: T+1 fully landed, B(T+2) stays in flight (counted, never 0 mid-loop)
            if (T < NT - 2)       asm volatile("s_waitcnt vmcnt(4)" ::: "memory");
            else if (T == NT - 2) asm volatile("s_waitcnt vmcnt(0)" ::: "memory");
            fence_bar();
        }
    }

    // ---- epilogue (32-bit offsets) ----
    const int rbase = m0 + wr * 128 + (lane >> 4) * 4;
    if (MODE == 1) {
        const int g = ntl >> 1;   // 0:att 1:r 2:r1
        const float* bias = (g == 0) ? bias0 : (g == 1) ? bias1 : bias2;
        const int ncb = (ntl & 1) * 256 + wc * 64;
#pragma unroll
        for (int i = 0; i < 8; ++i)
#pragma unroll
            for (int j = 0; j < 4; ++j) {
                const int nn = ncb + j * 16 + fr;
                const float b = bias[nn];
                int off = (rbase + i * 16) * 512 + nn;
#pragma unroll
                for (int jj = 0; jj < 4; ++jj, off += 512) {
                    float v = acc[i][j][jj] + b;
                    float s = 1.0f / (1.0f + __expf(-v));
                    if (g == 0)      outp[off] = s;
                    else if (g == 1) hrw[off]  = f2bf(s * bf2f(HbP[off]));
                    else             pr1w[off] = f2bf(s * bf2f(PbP[off]));
                }
            }
    } else {
        const int ncb = n0 + wc * 64;
#pragma unroll
        for (int i = 0; i < 8; ++i)
#pragma unroll
            for (int j = 0; j < 4; ++j) {
                const int nn = ncb + j * 16 + fr;
                const float b = bias0[nn];
                int off = (rbase + i * 16) * 512 + nn;
#pragma unroll
                for (int jj = 0; jj < 4; ++jj, off += 512) {
                    float v = acc[i][j][jj] + b;
                    float e = __expf(2.0f * v);
                    float ct = 1.0f - 2.0f / (e + 1.0f);   // tanh, inf-safe
                    float a = outp[off];                     // att parked by k1
                    float h = bf2f(HbP[off]);                // h from bf16 cast
                    outp[off] = a * ct + (1.0f - a) * h;
                }
            }
    }
}

// =============== small-ws fallback: proven R2 128x128 kernels ===============
__global__ __launch_bounds__(256, 2)
void k1_small(const float* __restrict__ X, const float* __restrict__ H,
              const float* __restrict__ P, const u16* __restrict__ B1,
              const float* __restrict__ ba, const float* __restrict__ br,
              const float* __restrict__ br1,
              float* __restrict__ attf, u16* __restrict__ hrw, u16* __restrict__ pr1w)
{
    __shared__ u16 Ab[2][128 * 64];
    __shared__ u16 Bb[2][128 * 64];
    const int tid = threadIdx.x, lane = tid & 63, w = tid >> 6;
    const int wr = w >> 1, wc = w & 1;
    const int bid = blockIdx.x, xcd = bid & 7, idx = bid >> 3;
    const int panel = idx / 12, ntl = idx - panel * 12;
    const int m0 = (xcd * 64 + panel) * 128, n0 = ntl * 128;
    const int srow = w * 32 + (lane >> 3);
    const int scol = ((lane & 7) ^ (lane >> 3)) * 8;
    const int arow = tid >> 4, acol = (tid & 15) * 4;
    const int aswz = acol ^ ((arow & 7) << 3);
    f32x4 acc[4][4];
    const f32x4 vz = {0, 0, 0, 0};
#pragma unroll
    for (int i = 0; i < 4; ++i)
#pragma unroll
        for (int j = 0; j < 4; ++j) acc[i][j] = vz;
    f32x4 areg[8];
    auto issueA = [&](int kt) {
        const float* src = (kt < 8) ? X : (kt < 16) ? H : P;
        const float* base = src + (size_t)(m0 + arow) * 512 + (kt & 7) * 64 + acol;
#pragma unroll
        for (int rr = 0; rr < 8; ++rr)
            areg[rr] = *(const f32x4*)(base + (size_t)(rr * 16) * 512);
    };
    auto writeA = [&](int nb) {
#pragma unroll
        for (int rr = 0; rr < 8; ++rr) {
            uint2 q; q.x = f2bf2(areg[rr].x, areg[rr].y);
            q.y = f2bf2(areg[rr].z, areg[rr].w);
            *(uint2*)&Ab[nb][(arow + rr * 16) * 64 + aswz] = q;
        }
    };
    auto issueB = [&](int kt, int nb) {
        const u16* gb = B1 + (size_t)(n0 + srow) * 1536 + kt * 64 + scol;
        u16* lb = &Bb[nb][(w * 32) * 64];
#pragma unroll
        for (int c = 0; c < 4; ++c)
            load_lds16(gb + (size_t)c * 8 * 1536, lb + c * 8 * 64);
    };
    auto compute = [&](int cb) {
        const int rsw = (lane & 7) << 3, rb = lane & 15, hi8 = (lane >> 4) * 8;
#pragma unroll
        for (int ks = 0; ks < 2; ++ks) {
            bf16x8 af[4], bfr[4];
            const int col = (ks * 32 + hi8) ^ rsw;
#pragma unroll
            for (int fm = 0; fm < 4; ++fm)
                af[fm] = *(const bf16x8*)&Ab[cb][(wr * 64 + fm * 16 + rb) * 64 + col];
#pragma unroll
            for (int fn = 0; fn < 4; ++fn)
                bfr[fn] = *(const bf16x8*)&Bb[cb][(wc * 64 + fn * 16 + rb) * 64 + col];
#pragma unroll
            for (int fm = 0; fm < 4; ++fm)
#pragma unroll
                for (int fn = 0; fn < 4; ++fn)
                    acc[fm][fn] = __builtin_amdgcn_mfma_f32_16x16x32_bf16(
                        af[fm], bfr[fn], acc[fm][fn], 0, 0, 0);
        }
    };
    issueA(0); issueB(0, 0); writeA(0);
    __syncthreads();
    int cb = 0;
#pragma unroll 2
    for (int kt = 0; kt < 24; ++kt) {
        if (kt < 23) { issueA(kt + 1); issueB(kt + 1, cb ^ 1); }
        compute(cb);
        if (kt < 23) writeA(cb ^ 1);
        __syncthreads();
        cb ^= 1;
    }
    const int gate = ntl >> 2;
    const float* bias = (gate == 0) ? ba : (gate == 1) ? br : br1;
    const int nnb = (ntl & 3) * 128 + wc * 64;
    const int rl = (lane >> 4) * 4, cl = lane & 15;
#pragma unroll
    for (int fm = 0; fm < 4; ++fm)
#pragma unroll
        for (int fn = 0; fn < 4; ++fn) {
            const int nn = nnb + fn * 16 + cl;
            const float b = bias[nn];
#pragma unroll
            for (int j = 0; j < 4; ++j) {
                const int row = m0 + wr * 64 + fm * 16 + rl + j;
                const size_t off = (size_t)row * 512 + nn;
                float v = acc[fm][fn][j] + b;
                float s = 1.0f / (1.0f + __expf(-v));
                if (gate == 0)      attf[off] = s;
                else if (gate == 1) hrw[off]  = f2bf(s * H[off]);
                else                pr1w[off] = f2bf(s * P[off]);
            }
        }
}

__global__ __launch_bounds__(256, 2)
void k2_small(const float* __restrict__ X, const float* __restrict__ H,
              const u16* __restrict__ B2, const float* __restrict__ bc,
              const u16* __restrict__ hrw, const u16* __restrict__ pr1w,
              float* outp)
{
    __shared__ u16 Ab[2][128 * 64];
    __shared__ u16 Bb[2][128 * 64];
    const int tid = threadIdx.x, lane = tid & 63, w = tid >> 6;
    const int wr = w >> 1, wc = w & 1;
    const int bid = blockIdx.x, xcd = bid & 7, idx = bid >> 3;
    const int panel = idx >> 2, ntl = idx & 3;
    const int m0 = (xcd * 64 + panel) * 128, n0 = ntl * 128;
    const int srow = w * 32 + (lane >> 3);
    const int scol = ((lane & 7) ^ (lane >> 3)) * 8;
    const int arow = tid >> 4, acol = (tid & 15) * 4;
    const int aswz = acol ^ ((arow & 7) << 3);
    f32x4 acc[4][4];
    const f32x4 vz = {0, 0, 0, 0};
#pragma unroll
    for (int i = 0; i < 4; ++i)
#pragma unroll
        for (int j = 0; j < 4; ++j) acc[i][j] = vz;
    f32x4 areg[8];
    auto issueA = [&](int kt, int nb) {
        if (kt >= 8) {
            const u16* src = (kt < 16) ? hrw : pr1w;
            const u16* gb = src + (size_t)(m0 + srow) * 512 + (kt & 7) * 64 + scol;
            u16* lb = &Ab[nb][(w * 32) * 64];
#pragma unroll
            for (int c = 0; c < 4; ++c)
                load_lds16(gb + (size_t)c * 8 * 512, lb + c * 8 * 64);
        } else {
            const float* base = X + (size_t)(m0 + arow) * 512 + (kt & 7) * 64 + acol;
#pragma unroll
            for (int rr = 0; rr < 8; ++rr)
                areg[rr] = *(const f32x4*)(base + (size_t)(rr * 16) * 512);
        }
    };
    auto writeA = [&](int kt, int nb) {
        if (kt < 8) {
#pragma unroll
            for (int rr = 0; rr < 8; ++rr) {
                uint2 q; q.x = f2bf2(areg[rr].x, areg[rr].y);
                q.y = f2bf2(areg[rr].z, areg[rr].w);
                *(uint2*)&Ab[nb][(arow + rr * 16) * 64 + aswz] = q;
            }
        }
    };
    auto issueB = [&](int kt, int nb) {
        const u16* gb = B2 + (size_t)(n0 + srow) * 1536 + kt * 64 + scol;
        u16* lb = &Bb[nb][(w * 32) * 64];
#pragma unroll
        for (int c = 0; c < 4; ++c)
            load_lds16(gb + (size_t)c * 8 * 1536, lb + c * 8 * 64);
    };
    auto compute = [&](int cb) {
        const int rsw = (lane & 7) << 3, rb = lane & 15, hi8 = (lane >> 4) * 8;
#pragma unroll
        for (int ks = 0; ks < 2; ++ks) {
            bf16x8 af[4], bfr[4];
            const int col = (ks * 32 + hi8) ^ rsw;
#pragma unroll
            for (int fm = 0; fm < 4; ++fm)
                af[fm] = *(const bf16x8*)&Ab[cb][(wr * 64 + fm * 16 + rb) * 64 + col];
#pragma unroll
            for (int fn = 0; fn < 4; ++fn)
                bfr[fn] = *(const bf16x8*)&Bb[cb][(wc * 64 + fn * 16 + rb) * 64 + col];
#pragma unroll
            for (int fm = 0; fm < 4; ++fm)
#pragma unroll
                for (int fn = 0; fn < 4; ++fn)
                    acc[fm][fn] = __builtin_amdgcn_mfma_f32_16x16x32_bf16(
                        af[fm], bfr[fn], acc[fm][fn], 0, 0, 0);
        }
    };
    issueA(0, 0); issueB(0, 0); writeA(0, 0);
    __syncthreads();
    int cb = 0;
#pragma unroll 2
    for (int kt = 0; kt < 24; ++kt) {
        if (kt < 23) { issueA(kt + 1, cb ^ 1); issueB(kt + 1, cb ^ 1); }
        compute(cb);
        if (kt < 23) writeA(kt + 1, cb ^ 1);
        __syncthreads();
        cb ^= 1;
    }
    const int nnb = n0 + wc * 64;
    const int rl = (lane >> 4) * 4, cl = lane & 15;
#pragma unroll
    for (int fm = 0; fm < 4; ++fm)
#pragma unroll
        for (int fn = 0; fn < 4; ++fn) {
            const int nn = nnb + fn * 16 + cl;
            const float b = bc[nn];
#pragma unroll
            for (int j = 0; j < 4; ++j) {
                const int row = m0 + wr * 64 + fm * 16 + rl + j;
                const size_t off = (size_t)row * 512 + nn;
                float v = acc[fm][fn][j] + b;
                float e = __expf(2.0f * v);
                float ct = 1.0f - 2.0f / (e + 1.0f);
                float a = outp[off];
                outp[off] = a * ct + (1.0f - a) * H[off];
            }
        }
}

extern "C" void kernel_launch(void* const* d_in, const int* in_sizes, int n_in,
                              void* d_out, int out_size, void* d_ws, size_t ws_size,
                              hipStream_t stream)
{
    const float* X   = (const float*)d_in[0];
    const float* H   = (const float*)d_in[1];
    const float* P   = (const float*)d_in[2];
    const float* wa  = (const float*)d_in[3];
    const float* ba  = (const float*)d_in[4];
    const float* wrg = (const float*)d_in[5];
    const float* br  = (const float*)d_in[6];
    const float* wr1 = (const float*)d_in[7];
    const float* br1 = (const float*)d_in[8];
    const float* wcc = (const float*)d_in[9];
    const float* bc  = (const float*)d_in[10];
    const float* ua  = (const float*)d_in[11];
    const float* ur  = (const float*)d_in[12];
    const float* ur1 = (const float*)d_in[13];
    const float* uc  = (const float*)d_in[14];
    const float* pa  = (const float*)d_in[15];
    const float* pr  = (const float*)d_in[16];
    const float* pr1 = (const float*)d_in[17];
    const float* pc  = (const float*)d_in[18];

    char* ws = (char*)d_ws;
    u16* B1   = (u16*)(ws);
    u16* B2   = (u16*)(ws + (size_t)4718592);
    u16* hrp  = (u16*)(ws + (size_t)6291456);
    u16* pr1p = (u16*)(ws + (size_t)73400320);
    u16* Xb   = (u16*)(ws + (size_t)140509184);
    u16* Hb   = (u16*)(ws + (size_t)207618048);
    u16* Pb   = (u16*)(ws + (size_t)274726912);
    float* out = (float*)d_out;

    const bool big = ws_size >= (size_t)341835776ULL;

    prep_weights<<<12288, 256, 0, stream>>>(wa, ua, pa, wrg, ur, pr, wr1, ur1, pr1,
                                            wcc, uc, pc, B1, B2);
    if (big) {
        cast_inputs<<<3072, 256, 0, stream>>>(X, H, P, Xb, Hb, Pb);
        gemm256<1><<<1536, 512, 0, stream>>>(Xb, Hb, Pb, B1, ba, br, br1,
                                             Hb, Pb, out, hrp, pr1p);
        gemm256<2><<<512, 512, 0, stream>>>(Xb, hrp, pr1p, B2, bc, nullptr, nullptr,
                                            Hb, nullptr, out, nullptr, nullptr);
    } else {
        k1_small<<<6144, 256, 0, stream>>>(X, H, P, B1, ba, br, br1, out, hrp, pr1p);
        k2_small<<<2048, 256, 0, stream>>>(X, H, B2, bc, hrp, pr1p, out);
    }
}